// Round 15
// baseline (1943.883 us; speedup 1.0000x reference)
//
#include <hip/hip_runtime.h>
#include <stdint.h>

#define NROWS 8192
#define DDIM  256
#define K2    512          // [hi | lo] packed per row
#define MARGIN_F 0.2f

typedef short  short8  __attribute__((ext_vector_type(8)));
typedef float  floatx4 __attribute__((ext_vector_type(4)));

// Static device buffers (avoid depending on ws_size).
__device__ unsigned short gA[(size_t)NROWS * K2];   // im split: [hi | lo]
__device__ unsigned short gB[(size_t)NROWS * K2];   // s  split: [hi | lo]
__device__ float    g_diag[NROWS];
__device__ unsigned g_rowcnt[NROWS];
__device__ unsigned g_rowkey[NROWS];
__device__ unsigned g_colcnt[NROWS];
__device__ unsigned g_colkey[NROWS];

__device__ __forceinline__ unsigned short f2bf_rne(float x){
    unsigned u = __float_as_uint(x);
    return (unsigned short)((u + 0x7FFFu + ((u >> 16) & 1u)) >> 16);
}
__device__ __forceinline__ float bf2f(unsigned short h){
    return __uint_as_float(((unsigned)h) << 16);
}
// monotone float -> uint key (order-preserving), so atomicMax works on floats
__device__ __forceinline__ unsigned fkey(float f){
    unsigned u = __float_as_uint(f);
    return (u & 0x80000000u) ? ~u : (u | 0x80000000u);
}
__device__ __forceinline__ float kinv(unsigned k){
    unsigned u = (k & 0x80000000u) ? (k ^ 0x80000000u) : ~k;
    return __uint_as_float(u);
}

__device__ __forceinline__ void load_lds16(const unsigned short* gptr, void* lptr){
    __builtin_amdgcn_global_load_lds(
        (const __attribute__((address_space(1))) unsigned int*)(uintptr_t)gptr,
        (__attribute__((address_space(3))) unsigned int*)(unsigned)(uintptr_t)lptr,
        16, 0, 0);
}

// One wave per row: fp32 diag dot, hi/lo bf16 split, stats init.
__global__ __launch_bounds__(256) void prep_kernel(const float* __restrict__ im,
                                                   const float* __restrict__ s){
    const int w    = threadIdx.x >> 6;
    const int lane = threadIdx.x & 63;
    const int row  = blockIdx.x * 4 + w;

    const float4 a = ((const float4*)(im + (size_t)row * DDIM))[lane];
    const float4 b = ((const float4*)(s  + (size_t)row * DDIM))[lane];

    float dp = a.x*b.x + a.y*b.y + a.z*b.z + a.w*b.w;
    #pragma unroll
    for (int m = 1; m < 64; m <<= 1) dp += __shfl_xor(dp, m, 64);
    if (lane == 0){
        g_diag[row]   = dp;
        g_rowcnt[row] = 0u; g_rowkey[row] = 0u;
        g_colcnt[row] = 0u; g_colkey[row] = 0u;
    }

    float av[4] = {a.x, a.y, a.z, a.w};
    float bv[4] = {b.x, b.y, b.z, b.w};
    unsigned short ah[4], al[4], bh[4], bl[4];
    #pragma unroll
    for (int i = 0; i < 4; ++i){
        ah[i] = f2bf_rne(av[i]); al[i] = f2bf_rne(av[i] - bf2f(ah[i]));
        bh[i] = f2bf_rne(bv[i]); bl[i] = f2bf_rne(bv[i] - bf2f(bh[i]));
    }
    const size_t base = (size_t)row * K2 + lane * 4;
    *(ushort4*)&gA[base      ] = make_ushort4(ah[0], ah[1], ah[2], ah[3]);
    *(ushort4*)&gA[base + 256] = make_ushort4(al[0], al[1], al[2], al[3]);
    *(ushort4*)&gB[base      ] = make_ushort4(bh[0], bh[1], bh[2], bh[3]);
    *(ushort4*)&gB[base + 256] = make_ushort4(bl[0], bl[1], bl[2], bl[3]);
}

// B-RESIDENT GEMM — entire 64-col B tile (hi+lo, full K) lives in LDS (64KB),
// staged in ONE phase with ONE barrier; the K-loop has NO barriers at all.
// 256x64 output tile, 512 threads = 8 waves x (32 private rows x 64 cols).
// Per t-step (8 total): A hi/lo frags global->reg in MFMA layout (read exactly
// once, one-ahead prefetch), 8 batched ds_read_b128, 24 MFMA (3-term split).
// Rationale (R2-R14): every 4-phase chunked variant plateaued at gemm
// 182-215us regardless of bytes/occupancy/buffering/producer-consumer —
// the phase structure itself was the cost. Here phases are gone.
// Budget/CU (2 blocks): MFMA 14.9k cyc, LDS 35 B/cyc (<85), A vec 17 B/cyc
// (L2-resident via XCD bi-pinning), B DMA 4.4 B/cyc. acc 2x4 tiles = 32 regs;
// total ~110 < 128 cap of (512,4). LDS 66.8KB*2 <= 160. Swizzle: store chunk
// (c&~7)|((c&7)^(row&7)) -> 2-way bank aliasing (free).
__global__ __launch_bounds__(512, 4) void gemm_stats_kernel(){
    __shared__ unsigned short Bs[64 * K2];   // full B tile: 64 cols x K2 = 64KB
    __shared__ float drow[256];
    __shared__ float dcol[64];

    const int tid = threadIdx.x;
    const int bid = blockIdx.x;
    // XCD-pinned A-rows: bi = xcd*4 + p; bj sweeps fastest -> 256KB A working
    // set stays L2-resident per XCD while B streams through DMA.
    const int bi  = (bid & 7) * 4 + ((bid >> 3) & 3);   // 0..31 (256-row groups)
    const int bj  = bid >> 5;                           // 0..127 (64-col tiles)

    if (tid < 256)      drow[tid]       = g_diag[bi * 256 + tid];
    else if (tid < 320) dcol[tid - 256] = g_diag[bj * 64 + (tid - 256)];

    const unsigned short* Bbase = gB + (size_t)bj * 64 * K2;

    // ---- stage FULL B tile once: 4096 16B chunks over 512 threads ----
    #pragma unroll
    for (int q = 0; q < 8; ++q){
        const int ch   = q * 512 + tid;               // chunk 0..4095
        const int r    = ch >> 6;                     // B row (output col) 0..63
        const int cst  = ch & 63;                     // stored chunk pos in row
        const int clog = (cst & 56) | ((cst & 7) ^ (r & 7));
        load_lds16(Bbase + (size_t)r * K2 + clog * 8, (char*)Bs + ch * 16);
    }
    __syncthreads();   // the ONLY barrier (covered by the other resident block)

    const int w    = tid >> 6, lane = tid & 63;   // w in 0..7
    const int quad = lane >> 4, l16 = lane & 15;
    const int sw   = l16 & 7;

    floatx4 acc[2][4] = {};

    const unsigned short* AhFrag = gA + (size_t)(bi * 256 + w * 32 + l16) * K2 + quad * 8;
    const unsigned short* AlFrag = AhFrag + 256;

    short8 ah[2][2], al[2][2];     // [buf][mi], one t-step ahead
    #pragma unroll
    for (int mi = 0; mi < 2; ++mi){
        ah[0][mi] = *(const short8*)(AhFrag + (size_t)(mi * 16) * K2);
        al[0][mi] = *(const short8*)(AlFrag + (size_t)(mi * 16) * K2);
    }
    int cur = 0;

    #pragma unroll 1
    for (int t = 0; t < 8; ++t){
        if (t < 7){
            const size_t noff = (size_t)(t + 1) * 32;
            #pragma unroll
            for (int mi = 0; mi < 2; ++mi){
                ah[cur ^ 1][mi] = *(const short8*)(AhFrag + (size_t)(mi * 16) * K2 + noff);
                al[cur ^ 1][mi] = *(const short8*)(AlFrag + (size_t)(mi * 16) * K2 + noff);
            }
        }

        // stored chunk position for logical chunk t*4+quad (hi) / +32 (lo)
        const int coff = (t >> 1) * 64 + ((((t & 1) * 4 + quad) ^ sw) * 8);
        short8 bh4[4], bl4[4];
        #pragma unroll
        for (int nj = 0; nj < 4; ++nj){
            bh4[nj] = *(const short8*)&Bs[(nj * 16 + l16) * K2 + coff];
            bl4[nj] = *(const short8*)&Bs[(nj * 16 + l16) * K2 + coff + 256];
        }
        // pass 1: Ah*Bh
        #pragma unroll
        for (int nj = 0; nj < 4; ++nj){
            acc[0][nj] = __builtin_amdgcn_mfma_f32_16x16x32_bf16(ah[cur][0], bh4[nj], acc[0][nj], 0, 0, 0);
            acc[1][nj] = __builtin_amdgcn_mfma_f32_16x16x32_bf16(ah[cur][1], bh4[nj], acc[1][nj], 0, 0, 0);
        }
        // pass 2: Al*Bh
        #pragma unroll
        for (int nj = 0; nj < 4; ++nj){
            acc[0][nj] = __builtin_amdgcn_mfma_f32_16x16x32_bf16(al[cur][0], bh4[nj], acc[0][nj], 0, 0, 0);
            acc[1][nj] = __builtin_amdgcn_mfma_f32_16x16x32_bf16(al[cur][1], bh4[nj], acc[1][nj], 0, 0, 0);
        }
        // pass 3: Ah*Bl
        #pragma unroll
        for (int nj = 0; nj < 4; ++nj){
            acc[0][nj] = __builtin_amdgcn_mfma_f32_16x16x32_bf16(ah[cur][0], bl4[nj], acc[0][nj], 0, 0, 0);
            acc[1][nj] = __builtin_amdgcn_mfma_f32_16x16x32_bf16(ah[cur][1], bl4[nj], acc[1][nj], 0, 0, 0);
        }
        cur ^= 1;
    }

    // ---- fused stats epilogue ----
    // C/D layout (verified m89/m91): col = lane&15, row = quad*4 + reg.
    // acc[mi][nj]: row = w*32 + mi*16 + quad*4 + r ; col = nj*16 + l16.
    const int rowbase = bi * 256 + w * 32;
    const int colbase = bj * 64;

    // row stats: each lane holds 4 cols (nj); reduce across l16 lanes.
    #pragma unroll
    for (int mi = 0; mi < 2; ++mi){
        #pragma unroll
        for (int r = 0; r < 4; ++r){
            const int lrow = w * 32 + mi * 16 + quad * 4 + r;
            const int gi   = bi * 256 + lrow;
            const float dv = drow[lrow];
            int cnt = 0; float mx = -3.0e38f;
            #pragma unroll
            for (int nj = 0; nj < 4; ++nj){
                const float v  = acc[mi][nj][r];
                const int   gj = colbase + nj * 16 + l16;
                if (gi != gj){                 // exclude diagonal explicitly
                    cnt += (v < dv) ? 1 : 0;
                    mx = fmaxf(mx, v);
                }
            }
            #pragma unroll
            for (int m = 1; m < 16; m <<= 1){
                cnt += __shfl_xor(cnt, m, 64);
                mx   = fmaxf(mx, __shfl_xor(mx, m, 64));
            }
            if (l16 == 0){
                atomicAdd(&g_rowcnt[gi], (unsigned)cnt);
                atomicMax(&g_rowkey[gi], fkey(mx));
            }
        }
    }
    // col stats: each lane holds 8 rows (mi,r) per nj; reduce across quad lanes.
    #pragma unroll
    for (int nj = 0; nj < 4; ++nj){
        const int lcol = nj * 16 + l16;
        const int gj   = bj * 64 + lcol;
        const float dv = dcol[lcol];
        int cnt = 0; float mx = -3.0e38f;
        #pragma unroll
        for (int mi = 0; mi < 2; ++mi){
            #pragma unroll
            for (int r = 0; r < 4; ++r){
                const float v  = acc[mi][nj][r];
                const int   gi = rowbase + mi * 16 + quad * 4 + r;
                if (gi != gj){
                    cnt += (v < dv) ? 1 : 0;
                    mx = fmaxf(mx, v);
                }
            }
        }
        #pragma unroll
        for (int m = 16; m < 64; m <<= 1){
            cnt += __shfl_xor(cnt, m, 64);
            mx   = fmaxf(mx, __shfl_xor(mx, m, 64));
        }
        if (quad == 0){
            atomicAdd(&g_colcnt[gj], (unsigned)cnt);
            atomicMax(&g_colkey[gj], fkey(mx));
        }
    }
}

__global__ __launch_bounds__(256) void finalize_kernel(float* __restrict__ out){
    __shared__ double red[256];
    double acc = 0.0;
    #pragma unroll
    for (int it = 0; it < NROWS / 256; ++it){
        const int i = it * 256 + threadIdx.x;
        const float d  = g_diag[i];
        const float cs  = fmaxf(MARGIN_F + kinv(g_rowkey[i]) - d, 0.0f) * (1.0f / (float)(g_rowcnt[i] + 1u));
        const float cim = fmaxf(MARGIN_F + kinv(g_colkey[i]) - d, 0.0f) * (1.0f / (float)(g_colcnt[i] + 1u));
        acc += (double)cs + (double)cim;
    }
    red[threadIdx.x] = acc;
    __syncthreads();
    for (int s2 = 128; s2 > 0; s2 >>= 1){
        if (threadIdx.x < s2) red[threadIdx.x] += red[threadIdx.x + s2];
        __syncthreads();
    }
    if (threadIdx.x == 0) out[0] = (float)red[0];
}

extern "C" void kernel_launch(void* const* d_in, const int* in_sizes, int n_in,
                              void* d_out, int out_size, void* d_ws, size_t ws_size,
                              hipStream_t stream){
    const float* im = (const float*)d_in[0];
    const float* s  = (const float*)d_in[1];
    float* out = (float*)d_out;

    prep_kernel<<<NROWS / 4, 256, 0, stream>>>(im, s);
    gemm_stats_kernel<<<4096, 512, 0, stream>>>();
    finalize_kernel<<<1, 256, 0, stream>>>(out);
}